// Round 5
// baseline (126.318 us; speedup 1.0000x reference)
//
#include <hip/hip_runtime.h>
#include <hip/hip_bf16.h>

#define D 128
#define TPW 4                 // 16-row tiles per wave
#define ROWS_PER_BLOCK 256    // 4 waves x 64 rows; grid 512 = 2 blocks/CU

typedef __attribute__((ext_vector_type(8))) short short8;
typedef __attribute__((ext_vector_type(4))) float float4_t;

typedef const __attribute__((address_space(1))) void g_void;
typedef __attribute__((address_space(3))) void l_void;

// ---------------------------------------------------------------------------
// Kernel 1: fold the 4 candidate ops into one combined matrix/bias.
// ---------------------------------------------------------------------------
__global__ void combine_kernel(const float* __restrict__ W,
                               const float* __restrict__ b,
                               const float* __restrict__ wts,
                               __hip_bfloat16* __restrict__ Wc,
                               float* __restrict__ bc) {
    int idx = blockIdx.x * blockDim.x + threadIdx.x;
    float w0 = wts[0], w1 = wts[1], w2 = wts[2], w3 = wts[3];
    if (idx < D * D) {
        float v = w0 * W[idx] + w1 * W[D * D + idx]
                + w2 * W[2 * D * D + idx] + w3 * W[3 * D * D + idx];
        Wc[idx] = __float2bfloat16(v);
    }
    if (idx < D) {
        bc[idx] = w0 * b[idx] + w1 * b[D + idx] + w2 * b[2 * D + idx] + w3 * b[3 * D + idx];
    }
}

__device__ __forceinline__ short8 cvt8_bf16(float4_t a, float4_t b) {
    union { short8 s; __hip_bfloat16 h[8]; } u;
    u.h[0] = __float2bfloat16(a[0]);
    u.h[1] = __float2bfloat16(a[1]);
    u.h[2] = __float2bfloat16(a[2]);
    u.h[3] = __float2bfloat16(a[3]);
    u.h[4] = __float2bfloat16(b[0]);
    u.h[5] = __float2bfloat16(b[1]);
    u.h[6] = __float2bfloat16(b[2]);
    u.h[7] = __float2bfloat16(b[3]);
    return u.s;
}

// ---------------------------------------------------------------------------
// Kernel 2: y[m][f] = sum_d x[m][d] * Wc[f][d] + bc[f]   (M = 131072)
//
// R4 post-mortem: async gll pipeline worked (gemm ~43 -> ~35 us) but the
// remaining gap is inter-wave coupling: waves read each other's staged
// rows, forcing 2 block-wide barriers per tile. This version makes each
// wave FULLY PRIVATE: 16-row tiles x all 128 cols (Wc entirely in
// registers, wf[8][4] = 128 VGPR), wave-private 2x8KB LDS double buffer,
// depth-1 counted-vmcnt prefetch. ZERO barriers — waves self-pace.
//
// vmcnt audit (in-order retirement, m135): step T waits stage(T); younger
// ops = stores(T-1) [8] -> vwait(8) steady state, vwait(0) only at T=0
// (prologue drain, also covers wf/bias loads which are older).
//
// LDS swizzle (both-sides, rule #21): LDS[row][slot] holds x[row][slot ^
// (row&7)]; stage pre-swizzles the GLOBAL source slot (dest stays linear
// for gll), reads XOR the same involution -> uniform 8 lanes/bank-group,
// zero conflicts; global coalescing preserved (permutation within a
// 512 B row = same cache lines).
// ---------------------------------------------------------------------------
__global__ __launch_bounds__(256, 2) void gemm_kernel(const float* __restrict__ x,
                                                      const __hip_bfloat16* __restrict__ Wc,
                                                      const float* __restrict__ bc,
                                                      float* __restrict__ y, int M) {
    __shared__ __align__(16) char Bs[4 * 2 * 8192];   // [wave][buf][8 KB] = 64 KB

    const int tid  = threadIdx.x;
    const int lane = tid & 63;
    const int wave = tid >> 6;
    const int r    = lane & 15;   // MFMA B-col = x row within tile
    const int quad = lane >> 4;
    const int half = lane >> 5;   // stage: which of the 2 rows per gll instr
    const int p    = lane & 31;   // stage: 16B slot within 512B row

    char* wbase = Bs + wave * 16384;

    const int row0 = blockIdx.x * ROWS_PER_BLOCK + wave * 64;  // wave's rows
    if (row0 >= M) return;
    const float* xw = x + (size_t)row0 * D;

    // ---- Wc -> registers: full 128 cols (8 f-blocks x 4 k-steps) ----
    short8 wf[8][4];
    #pragma unroll
    for (int f = 0; f < 8; f++)
        #pragma unroll
        for (int ks = 0; ks < 4; ks++)
            wf[f][ks] = *(const short8*)((const short*)Wc
                          + (f * 16 + r) * D + ks * 32 + quad * 8);

    // bias as accumulator-init values: acc[f][reg] = bc[f*16 + quad*4 + reg]
    float4_t bias[8];
    #pragma unroll
    for (int f = 0; f < 8; f++)
        bias[f] = *(const float4_t*)(bc + f * 16 + quad * 4);

    // swizzled LDS read offsets: row r, k-slot s = ks*8 + quad*2 + h
    int roff[4][2];
    #pragma unroll
    for (int ks = 0; ks < 4; ks++)
        #pragma unroll
        for (int h = 0; h < 2; h++)
            roff[ks][h] = r * 512 + (((ks * 8 + quad * 2 + h) ^ (r & 7)) << 4);

    // stage tile t -> wave-private buffer (t&1): 8 x global_load_lds x16B.
    // instr g covers rows g*2+half; dest linear (wave-uniform + lane*16).
#define STAGE(t) {                                                              \
        const char* tb = (const char*)(xw + (t) * 16 * D);                      \
        char* db = wbase + ((t) & 1) * 8192;                                    \
        _Pragma("unroll")                                                       \
        for (int g = 0; g < 8; g++) {                                           \
            int sr = g * 2 + half;                                              \
            const char* src = tb + sr * 512 + ((p ^ (sr & 7)) << 4);            \
            __builtin_amdgcn_global_load_lds((g_void*)src,                      \
                                             (l_void*)(db + g * 1024), 16, 0, 0); \
        }                                                                       \
    }

    STAGE(0)

#define STEP(T, NW) {                                                           \
        asm volatile("s_waitcnt vmcnt(%0)" :: "i"(NW) : "memory");              \
        __builtin_amdgcn_sched_barrier(0);                                      \
        const char* buf = wbase + ((T) & 1) * 8192;                             \
        short8 xf[4];                                                           \
        _Pragma("unroll")                                                       \
        for (int ks = 0; ks < 4; ks++) {                                        \
            float4_t a0 = *(const float4_t*)(buf + roff[ks][0]);                \
            float4_t a1 = *(const float4_t*)(buf + roff[ks][1]);                \
            xf[ks] = cvt8_bf16(a0, a1);                                         \
        }                                                                       \
        asm volatile("s_waitcnt lgkmcnt(0)" ::: "memory");                      \
        __builtin_amdgcn_sched_barrier(0);                                      \
        if ((T) + 1 < TPW) STAGE((T) + 1)                                       \
        float4_t acc[8];                                                        \
        _Pragma("unroll")                                                       \
        for (int f = 0; f < 8; f++) acc[f] = bias[f];                           \
        _Pragma("unroll")                                                       \
        for (int ks = 0; ks < 4; ks++) {                                        \
            _Pragma("unroll")                                                   \
            for (int f = 0; f < 8; f++)                                         \
                acc[f] = __builtin_amdgcn_mfma_f32_16x16x32_bf16(               \
                    wf[f][ks], xf[ks], acc[f], 0, 0, 0);                        \
        }                                                                       \
        float* yp = y + (size_t)(row0 + (T) * 16 + r) * D + quad * 4;           \
        _Pragma("unroll")                                                       \
        for (int f = 0; f < 8; f++)                                             \
            *(float4_t*)(yp + f * 16) = acc[f];                                 \
    }

    STEP(0, 0)   // prologue drain: also covers wf/bias loads (older)
    STEP(1, 8)   // younger than stage(1): stores(0) = 8
    STEP(2, 8)
    STEP(3, 8)
#undef STEP
#undef STAGE
}

extern "C" void kernel_launch(void* const* d_in, const int* in_sizes, int n_in,
                              void* d_out, int out_size, void* d_ws, size_t ws_size,
                              hipStream_t stream) {
    const float* x   = (const float*)d_in[0];   // (B,S,D) fp32
    const float* W   = (const float*)d_in[1];   // (NOPS,D,D) fp32
    const float* b   = (const float*)d_in[2];   // (NOPS,D) fp32
    const float* wts = (const float*)d_in[3];   // (NOPS,) fp32
    float* y = (float*)d_out;

    __hip_bfloat16* Wc = (__hip_bfloat16*)d_ws;
    float* bc = (float*)((char*)d_ws + D * D * sizeof(__hip_bfloat16));

    combine_kernel<<<(D * D + 255) / 256, 256, 0, stream>>>(W, b, wts, Wc, bc);

    const int M = in_sizes[0] / D;  // B*S = 131072
    gemm_kernel<<<M / ROWS_PER_BLOCK, 256, 0, stream>>>(x, Wc, bc, y, M);
}